// Round 7
// baseline (176.220 us; speedup 1.0000x reference)
//
#include <hip/hip_runtime.h>
#include <math.h>

#define NGRAPH 256
#define HEADS  8
#define DIN    512
#define EPG    256   // edges per graph
#define NEDGE  65536
#define LOG2E 1.44269504088896341f
#define LN2   0.69314718055994531f

typedef short bf16x8 __attribute__((ext_vector_type(8)));
typedef float f32x4 __attribute__((ext_vector_type(4)));

__device__ __forceinline__ float softplusf(float v) {
    if (v > 20.f) return v;
    float t = exp2f(v * LOG2E);
    return LN2 * log2f(1.f + t);
}
__device__ __forceinline__ unsigned short f2bf(float f) {   // RNE f32 -> bf16
    union { float f; unsigned u; } c; c.f = f;
    unsigned r = c.u + 0x7fffu + ((c.u >> 16) & 1u);
    return (unsigned short)(r >> 16);
}
__device__ __forceinline__ float bf2f(unsigned short h) {
    union { float f; unsigned u; } c; c.u = ((unsigned)h) << 16;
    return c.f;
}
// XOR-swizzle for [64][64] bf16 tile (16B-group granularity) — Xt / Wl.
__device__ __forceinline__ int swz_idx(int row, int t) {
    int g = ((t >> 3) ^ (row ^ (row >> 3))) & 7;
    return (row << 6) | (g << 3) | (t & 7);
}
// Load 8 consecutive f32, split into bf16 hi + bf16 lo (truncation + residual).
__device__ __forceinline__ void loadsplit(const float* p, bf16x8& hi, bf16x8& lo) {
    float4 u = *(const float4*)p;
    float4 v = *(const float4*)(p + 4);
    float vv[8] = {u.x, u.y, u.z, u.w, v.x, v.y, v.z, v.w};
    #pragma unroll
    for (int j = 0; j < 8; ++j) {
        union { float f; unsigned q; } c; c.f = vv[j];
        unsigned hb = c.q & 0xffff0000u;
        hi[j] = (short)(unsigned short)(hb >> 16);
        union { float f; unsigned q; } d; d.q = hb;
        union { float f; unsigned q; } e2; e2.f = vv[j] - d.f;
        lo[j] = (short)(unsigned short)(e2.q >> 16);
    }
}

// One block per graph; 1024 threads = 16 waves = 4 waves/SIMD.
// Waves 0-7  ("head" waves):   full per-head path for head w.
// Waves 8-15 ("helper" waves): CB producer tiles + GEMM rows 32-63 of head w-8.
// LDS = 161,792 B. Two barriers total.
__global__ __launch_bounds__(1024, 4) void dag_ws_v5(
        const float* __restrict__ x,
        const float* __restrict__ Bm,
        const float* __restrict__ Cm,
        const float* __restrict__ dt,
        const float* __restrict__ dt_edge,
        const float* __restrict__ dt_bias,
        const float* __restrict__ Dp,
        const float* __restrict__ dag_masks,
        const int* __restrict__ edge_index,
        float* __restrict__ out) {
    __shared__ __align__(16) unsigned short CBsh[4096];   // CB[i][t] bf16 linear, 8 KB
    __shared__ __align__(16) unsigned short Xt[8][4096];  // X^T[e][t] bf16 swizzled, 64 KB
    __shared__ __align__(16) unsigned short Wl[8][4096];  // W[i][t]  bf16 swizzled, 64 KB
    __shared__ __align__(16) float Ab8[8][512];           // [i][8]: slot0=dnorm, slots1-7=band, 16 KB
    __shared__ float dts[8][64];
    __shared__ float dtt[8][64];
    __shared__ float ecsh[8][64];                         // per-head replica (wave-private)

    const int b = blockIdx.x;
    const int tid = threadIdx.x;
    const int w = tid >> 6;
    const int lane = tid & 63;
    const int lm = lane & 15;
    const int quad = lane >> 4;

    if (w < 8) {
        // ================= head wave: phase0 + scatter + Xt + normalize =========
        const float bias = dt_bias[w];
        {   // phase 0: node softplus + zero own arrays (all wave-private)
            float2 dv = *(const float2*)(dt + ((size_t)(b * 64 + lane)) * 16 + w * 2);
            dts[w][lane] = softplusf(dv.x + bias);
            dtt[w][lane] = softplusf(dv.y + bias);
            ecsh[w][lane] = 0.f;
            float4 z = make_float4(0.f, 0.f, 0.f, 0.f);
            *(float4*)(&Ab8[w][lane * 8]) = z;
            *(float4*)(&Ab8[w][lane * 8 + 4]) = z;
        }
        {   // edge scatter (own head, own replicas; dnorm -> band slot 0)
            #pragma unroll
            for (int eo = 0; eo < 4; ++eo) {
                int e = b * EPG + eo * 64 + lane;
                int sl = edge_index[e] & 63;
                int dl = edge_index[NEDGE + e] & 63;
                float mk = dag_masks[e];
                float de = softplusf(dt_edge[(size_t)e * HEADS + w] + bias);
                float dsum = (dts[w][sl] + dtt[w][dl] + de) * 0.57735026918962576451f; // 1/sqrt(3)
                float dexp = exp2f(-dsum * LOG2E);
                atomicAdd(&Ab8[w][dl * 8 + (dl - sl)], dexp * mk);   // dl-sl in [1,7]
                atomicAdd(&Ab8[w][dl * 8], dsum * mk);               // dnorm in slot 0
                atomicAdd(&ecsh[w][dl], mk);
            }
        }
        {   // Xt stage (wave-private), packed ds_write_b64
            const float* xg = x + (size_t)b * 64 * DIN + w * 64;
            #pragma unroll
            for (int r = 0; r < 4; ++r) {
                int t0 = quad * 4 + r * 16;   // multiple of 4
                int e0 = lm * 4;
                float4 v0 = *(const float4*)(xg + (size_t)(t0 + 0) * DIN + e0);
                float4 v1 = *(const float4*)(xg + (size_t)(t0 + 1) * DIN + e0);
                float4 v2 = *(const float4*)(xg + (size_t)(t0 + 2) * DIN + e0);
                float4 v3 = *(const float4*)(xg + (size_t)(t0 + 3) * DIN + e0);
                float a0[4] = {v0.x, v0.y, v0.z, v0.w};
                float a1[4] = {v1.x, v1.y, v1.z, v1.w};
                float a2[4] = {v2.x, v2.y, v2.z, v2.w};
                float a3[4] = {v3.x, v3.y, v3.z, v3.w};
                #pragma unroll
                for (int k = 0; k < 4; ++k) {
                    unsigned long long pk =
                          (unsigned long long)f2bf(a0[k])
                        | ((unsigned long long)f2bf(a1[k]) << 16)
                        | ((unsigned long long)f2bf(a2[k]) << 32)
                        | ((unsigned long long)f2bf(a3[k]) << 48);
                    *(unsigned long long*)(&Xt[w][swz_idx(e0 + k, t0)]) = pk;
                }
            }
        }
        {   // band normalize (lane i = row i); slot0 (dnorm) untouched
            float eci = ecsh[w][lane];
            float4 a03 = *(const float4*)(&Ab8[w][lane * 8]);
            float4 a47 = *(const float4*)(&Ab8[w][lane * 8 + 4]);
            float sc[7];
            #pragma unroll
            for (int s = 0; s < 7; ++s) {
                int src = lane - 1 - s;
                float p = (src >= 0) ? eci * ecsh[w][src] : 1.f;
                sc[s] = fminf(1.f, rsqrtf(p));   // 1/max(1,sqrt(p)); p=0 -> 1
            }
            a03.y *= sc[0]; a03.z *= sc[1]; a03.w *= sc[2];
            a47.x *= sc[3]; a47.y *= sc[4]; a47.z *= sc[5]; a47.w *= sc[6];
            *(float4*)(&Ab8[w][lane * 8]) = a03;
            *(float4*)(&Ab8[w][lane * 8 + 4]) = a47;
        }
    } else {
        // ================= helper wave: CB producer (two 16x16 tiles) ===========
        const int hw = w - 8;
        const int mi = hw >> 1;
        const int ni0 = (hw & 1) * 2;
        const float* Cr = Cm + ((size_t)(b * 64 + mi * 16 + lm)) * DIN + quad * 8;
        const float* B0 = Bm + ((size_t)(b * 64 + ni0 * 16 + lm)) * DIN + quad * 8;
        const float* B1 = B0 + (size_t)16 * DIN;
        f32x4 acc0 = {0.f, 0.f, 0.f, 0.f};
        f32x4 acc1 = {0.f, 0.f, 0.f, 0.f};
        #pragma unroll 4
        for (int ks = 0; ks < 16; ++ks) {
            bf16x8 ah, al, b0h, b0l, b1h, b1l;
            loadsplit(Cr + ks * 32, ah, al);
            loadsplit(B0 + ks * 32, b0h, b0l);
            loadsplit(B1 + ks * 32, b1h, b1l);
            acc0 = __builtin_amdgcn_mfma_f32_16x16x32_bf16(ah, b0h, acc0, 0, 0, 0);
            acc0 = __builtin_amdgcn_mfma_f32_16x16x32_bf16(ah, b0l, acc0, 0, 0, 0);
            acc0 = __builtin_amdgcn_mfma_f32_16x16x32_bf16(al, b0h, acc0, 0, 0, 0);
            acc1 = __builtin_amdgcn_mfma_f32_16x16x32_bf16(ah, b1h, acc1, 0, 0, 0);
            acc1 = __builtin_amdgcn_mfma_f32_16x16x32_bf16(ah, b1l, acc1, 0, 0, 0);
            acc1 = __builtin_amdgcn_mfma_f32_16x16x32_bf16(al, b1h, acc1, 0, 0, 0);
        }
        // C/D layout: col = lane&15, row = quad*4 + r
        #pragma unroll
        for (int r = 0; r < 4; ++r) {
            int row = mi * 16 + quad * 4 + r;
            CBsh[row * 64 + ni0 * 16 + lm] = f2bf(acc0[r]);
            CBsh[row * 64 + (ni0 + 1) * 16 + lm] = f2bf(acc1[r]);
        }
    }

    __syncthreads();   // barrier 1: CBsh (helpers) + Xt (heads) published

    if (w < 8) {
        // ---- banded forward solve (lane j = column j); dn comes free in slot 0 ----
        const int j = lane;
        const float Dh = Dp[w];
        float mwin[7] = {0.f, 0.f, 0.f, 0.f, 0.f, 0.f, 0.f};
        float4 a03 = *(const float4*)(&Ab8[w][0]);      // {dn0, A[0][..]} (row 0 band = 0)
        float4 a47 = *(const float4*)(&Ab8[w][4]);
        float cbv = bf2f(CBsh[j]);
        #pragma unroll 2
        for (int i = 0; i < 64; ++i) {
            float4 n03, n47;
            float ncb = 0.f;
            if (i < 63) {
                n03 = *(const float4*)(&Ab8[w][(i + 1) * 8]);
                n47 = *(const float4*)(&Ab8[w][(i + 1) * 8 + 4]);
                ncb = bf2f(CBsh[(i + 1) * 64 + j]);
            } else {
                n03 = make_float4(0.f, 0.f, 0.f, 0.f);
                n47 = n03;
            }
            float diag = (j == i) ? 1.f : 0.f;
            float t0 = fmaf(a03.y, mwin[0], fmaf(a03.z, mwin[1], diag));
            float t1 = fmaf(a03.w, mwin[2], fmaf(a47.x, mwin[3], a47.y * mwin[4]));
            float t2 = fmaf(a47.z, mwin[5], a47.w * mwin[6]);
            float mi_ = t0 + (t1 + t2);
            float wv = mi_ * cbv * a03.x;              // a03.x = dnorm[i]
            if (j == i) wv += Dh;
            Wl[w][swz_idx(i, j)] = f2bf(wv);           // i uniform -> conflict-free
            #pragma unroll
            for (int s = 6; s > 0; --s) mwin[s] = mwin[s - 1];
            mwin[0] = mi_;
            a03 = n03; a47 = n47; cbv = ncb;
        }
    }

    __syncthreads();   // barrier 2: Wl published

    // ---- GEMM y = W·X, split: head wave -> rows 0-31, helper wave -> rows 32-63 ----
    {
        const int head = (w < 8) ? w : (w - 8);
        const int m2base = (w < 8) ? 0 : 2;
        bf16x8 bfr[4][2];
        #pragma unroll
        for (int eb = 0; eb < 4; ++eb) {
            int er = eb * 16 + lm;
            bfr[eb][0] = *(const bf16x8*)(&Xt[head][swz_idx(er, quad * 8)]);
            bfr[eb][1] = *(const bf16x8*)(&Xt[head][swz_idx(er, 32 + quad * 8)]);
        }
        float* og = out + ((size_t)b * 64) * DIN + head * 64;
        #pragma unroll
        for (int m2o = 0; m2o < 2; ++m2o) {
            int row0 = (m2base + m2o) * 16 + lm;
            bf16x8 a0 = *(const bf16x8*)(&Wl[head][swz_idx(row0, quad * 8)]);
            bf16x8 a1 = *(const bf16x8*)(&Wl[head][swz_idx(row0, 32 + quad * 8)]);
            f32x4 acc[4];
            #pragma unroll
            for (int eb = 0; eb < 4; ++eb) {
                f32x4 z = {0.f, 0.f, 0.f, 0.f};
                z = __builtin_amdgcn_mfma_f32_16x16x32_bf16(a0, bfr[eb][0], z, 0, 0, 0);
                z = __builtin_amdgcn_mfma_f32_16x16x32_bf16(a1, bfr[eb][1], z, 0, 0, 0);
                acc[eb] = z;
            }
            #pragma unroll
            for (int r = 0; r < 4; ++r) {
                int row = (m2base + m2o) * 16 + quad * 4 + r;
                #pragma unroll
                for (int eb = 0; eb < 4; ++eb)
                    og[(size_t)row * DIN + eb * 16 + lm] = acc[eb][r];
            }
        }
    }
}

extern "C" void kernel_launch(void* const* d_in, const int* in_sizes, int n_in,
                              void* d_out, int out_size, void* d_ws, size_t ws_size,
                              hipStream_t stream) {
    (void)in_sizes; (void)n_in; (void)out_size; (void)d_ws; (void)ws_size;
    dag_ws_v5<<<dim3(NGRAPH), dim3(1024), 0, stream>>>(
        (const float*)d_in[0],   // x
        (const float*)d_in[1],   // B
        (const float*)d_in[2],   // C
        (const float*)d_in[3],   // dt
        (const float*)d_in[4],   // dt_edge
        (const float*)d_in[5],   // dt_bias
        (const float*)d_in[6],   // D
        (const float*)d_in[7],   // dag_masks
        (const int*)d_in[8],     // edge_index
        (float*)d_out);
}

// Round 8
// 163.599 us; speedup vs baseline: 1.0771x; 1.0771x over previous
//
#include <hip/hip_runtime.h>
#include <math.h>

#define NGRAPH 256
#define HEADS  8
#define DIN    512
#define EPG    256   // edges per graph
#define NEDGE  65536
#define LOG2E 1.44269504088896341f
#define LN2   0.69314718055994531f

typedef short bf16x8 __attribute__((ext_vector_type(8)));
typedef float f32x4 __attribute__((ext_vector_type(4)));
typedef unsigned long long u64;

__device__ __forceinline__ float softplusf(float v) {
    if (v > 20.f) return v;
    float t = exp2f(v * LOG2E);
    return LN2 * log2f(1.f + t);
}
__device__ __forceinline__ unsigned short f2bf(float f) {   // RNE f32 -> bf16
    union { float f; unsigned u; } c; c.f = f;
    unsigned r = c.u + 0x7fffu + ((c.u >> 16) & 1u);
    return (unsigned short)(r >> 16);
}
__device__ __forceinline__ float bf2f(unsigned short h) {
    union { float f; unsigned u; } c; c.u = ((unsigned)h) << 16;
    return c.f;
}
// XOR-swizzle for [64][64] bf16 tile (16B-group granularity) — stage tiles / Xt / Wl.
__device__ __forceinline__ int swz_idx(int row, int t) {
    int g = ((t >> 3) ^ (row ^ (row >> 3))) & 7;
    return (row << 6) | (g << 3) | (t & 7);
}
// split f32 -> bf16 hi (truncation) + bf16 lo (truncation of residual)
__device__ __forceinline__ void split1(float f, unsigned short& hi, unsigned short& lo) {
    union { float f; unsigned q; } c; c.f = f;
    unsigned hb = c.q & 0xffff0000u;
    hi = (unsigned short)(hb >> 16);
    union { float f; unsigned q; } d; d.q = hb;
    union { float f; unsigned q; } e2; e2.f = f - d.f;
    lo = (unsigned short)(e2.q >> 16);
}

// One block per graph, 512 threads = 8 waves, wave w owns head w end-to-end.
// ALL independent global loads issued at entry (T14 issue-early/write-late);
// CB operands register-staged 2 chunks deep into ping-pong LDS.
// LDS = 159,744 B.
__global__ __launch_bounds__(512, 2) void dag_pipe_v6(
        const float* __restrict__ x,
        const float* __restrict__ Bm,
        const float* __restrict__ Cm,
        const float* __restrict__ dt,
        const float* __restrict__ dt_edge,
        const float* __restrict__ dt_bias,
        const float* __restrict__ Dp,
        const float* __restrict__ dag_masks,
        const int* __restrict__ edge_index,
        float* __restrict__ out) {
    __shared__ __align__(16) unsigned short WS[32768];    // 64 KB: stage ping-pong -> Wl[8][4096]
    __shared__ __align__(16) unsigned short Xt[HEADS][4096]; // X^T[e][t] bf16 swizzled, 64 KB
    __shared__ __align__(16) unsigned short CBsh[4096];   // CB[i][t] bf16 linear, 8 KB
    __shared__ __align__(16) float Ab8[HEADS][512];       // [i][8]: slot0=dnorm, 1-7=band, 16 KB
    __shared__ float dts[HEADS][64];
    __shared__ float dtt[HEADS][64];
    __shared__ float ecsh[HEADS][64];                     // per-head replica (wave-private)

    const int b = blockIdx.x;
    const int tid = threadIdx.x;
    const int w = tid >> 6;       // wave id == head id
    const int lane = tid & 63;
    const int lm = lane & 15;
    const int quad = lane >> 4;
    const float bias = dt_bias[w];

    // ================= entry: issue ALL independent global loads =================
    float2 dv = *(const float2*)(dt + ((size_t)(b * 64 + lane)) * 16 + w * 2);

    // CB staging addressing (constant per thread): thread covers 16 consecutive
    // floats of one row of C (tid<256) or B (tid>=256) per chunk.
    const int u0 = tid * 4;
    const int mat = u0 >> 10;            // 0: C, 1: B (wave-uniform)
    const int srow = (u0 & 1023) >> 4;
    const int scol = (u0 & 15) << 2;     // float col within 64-col chunk
    const float* sp = (mat ? Bm : Cm) + ((size_t)(b * 64 + srow)) * DIN + scol;

    float4 pre0[4], pre1[4];             // chunks c and c+1 in flight
    #pragma unroll
    for (int i = 0; i < 4; ++i) pre0[i] = *(const float4*)(sp + 0 * 64 + 4 * i);
    #pragma unroll
    for (int i = 0; i < 4; ++i) pre1[i] = *(const float4*)(sp + 1 * 64 + 4 * i);

    int esl[4], edl[4]; float emk[4], edr[4];
    #pragma unroll
    for (int eo = 0; eo < 4; ++eo) {
        int e = b * EPG + eo * 64 + lane;
        esl[eo] = edge_index[e];
        edl[eo] = edge_index[NEDGE + e];
        emk[eo] = dag_masks[e];
        edr[eo] = dt_edge[(size_t)e * HEADS + w];
    }

    float4 xv[16];                       // full Xt tile slice in regs
    const float* xg = x + (size_t)b * 64 * DIN + w * 64;
    #pragma unroll
    for (int r = 0; r < 4; ++r) {
        int t0 = quad * 4 + r * 16;
        #pragma unroll
        for (int k = 0; k < 4; ++k)
            xv[r * 4 + k] = *(const float4*)(xg + (size_t)(t0 + k) * DIN + lm * 4);
    }

    // ================= phase 0 (wave-private) =================
    dts[w][lane] = softplusf(dv.x + bias);
    dtt[w][lane] = softplusf(dv.y + bias);
    ecsh[w][lane] = 0.f;
    {
        float4 z = make_float4(0.f, 0.f, 0.f, 0.f);
        *(float4*)(&Ab8[w][lane * 8]) = z;
        *(float4*)(&Ab8[w][lane * 8 + 4]) = z;
    }

    // ================= edge scatter (wave-private; dnorm -> band slot 0) ========
    #pragma unroll
    for (int eo = 0; eo < 4; ++eo) {
        int sl = esl[eo] & 63;
        int dl = edl[eo] & 63;
        float de = softplusf(edr[eo] + bias);
        float dsum = (dts[w][sl] + dtt[w][dl] + de) * 0.57735026918962576451f; // 1/sqrt(3)
        float dexp = exp2f(-dsum * LOG2E);
        atomicAdd(&Ab8[w][dl * 8 + (dl - sl)], dexp * emk[eo]);   // dl-sl in [1,7]
        atomicAdd(&Ab8[w][dl * 8], dsum * emk[eo]);               // dnorm in slot 0
        atomicAdd(&ecsh[w][dl], emk[eo]);
    }

    // ================= CB = C·B^T, register-staged 2-deep ping-pong =============
    const int mi = w >> 1;
    const int ni0 = (w & 1) * 2;
    f32x4 acc0 = {0.f, 0.f, 0.f, 0.f};
    f32x4 acc1 = {0.f, 0.f, 0.f, 0.f};
    #pragma unroll
    for (int c = 0; c < 8; ++c) {
        unsigned short* buf = WS + (c & 1) * 16384;
        unsigned short* thi = buf + mat * 8192;
        // write chunk c from registers (split to hi/lo bf16)
        #pragma unroll
        for (int i = 0; i < 4; ++i) {
            float4 v = (c & 1) ? pre1[i] : pre0[i];
            float a[4] = {v.x, v.y, v.z, v.w};
            u64 hp = 0, lp = 0;
            #pragma unroll
            for (int k = 0; k < 4; ++k) {
                unsigned short h, l;
                split1(a[k], h, l);
                hp |= ((u64)h) << (16 * k);
                lp |= ((u64)l) << (16 * k);
            }
            int idx = swz_idx(srow, scol + 4 * i);
            *(u64*)(thi + idx) = hp;
            *(u64*)(thi + 4096 + idx) = lp;
        }
        // issue chunk c+2 into the slot just freed (load->use ~2 chunk periods)
        if (c + 2 < 8) {
            #pragma unroll
            for (int i = 0; i < 4; ++i) {
                float4 nv = *(const float4*)(sp + (c + 2) * 64 + 4 * i);
                if (c & 1) pre1[i] = nv; else pre0[i] = nv;
            }
        }
        __syncthreads();    // publish chunk c
        const unsigned short* p = buf;
        #pragma unroll
        for (int ks = 0; ks < 2; ++ks) {
            int kl = ks * 32 + quad * 8;
            bf16x8 ah  = *(const bf16x8*)(p +         swz_idx(mi * 16 + lm, kl));
            bf16x8 al  = *(const bf16x8*)(p +  4096 + swz_idx(mi * 16 + lm, kl));
            bf16x8 b0h = *(const bf16x8*)(p +  8192 + swz_idx(ni0 * 16 + lm, kl));
            bf16x8 b0l = *(const bf16x8*)(p + 12288 + swz_idx(ni0 * 16 + lm, kl));
            bf16x8 b1h = *(const bf16x8*)(p +  8192 + swz_idx((ni0 + 1) * 16 + lm, kl));
            bf16x8 b1l = *(const bf16x8*)(p + 12288 + swz_idx((ni0 + 1) * 16 + lm, kl));
            acc0 = __builtin_amdgcn_mfma_f32_16x16x32_bf16(ah, b0h, acc0, 0, 0, 0);
            acc0 = __builtin_amdgcn_mfma_f32_16x16x32_bf16(ah, b0l, acc0, 0, 0, 0);
            acc0 = __builtin_amdgcn_mfma_f32_16x16x32_bf16(al, b0h, acc0, 0, 0, 0);
            acc1 = __builtin_amdgcn_mfma_f32_16x16x32_bf16(ah, b1h, acc1, 0, 0, 0);
            acc1 = __builtin_amdgcn_mfma_f32_16x16x32_bf16(ah, b1l, acc1, 0, 0, 0);
            acc1 = __builtin_amdgcn_mfma_f32_16x16x32_bf16(al, b1h, acc1, 0, 0, 0);
        }
    }
    // C/D layout: col = lane&15, row = quad*4 + r
    #pragma unroll
    for (int r = 0; r < 4; ++r) {
        int row = mi * 16 + quad * 4 + r;
        CBsh[row * 64 + ni0 * 16 + lm] = f2bf(acc0[r]);
        CBsh[row * 64 + (ni0 + 1) * 16 + lm] = f2bf(acc1[r]);
    }

    // ================= Xt convert+write from regs (wave-private) ================
    {
        int e0 = lm * 4;
        #pragma unroll
        for (int r = 0; r < 4; ++r) {
            int t0 = quad * 4 + r * 16;
            float A0[4] = {xv[r*4+0].x, xv[r*4+0].y, xv[r*4+0].z, xv[r*4+0].w};
            float A1[4] = {xv[r*4+1].x, xv[r*4+1].y, xv[r*4+1].z, xv[r*4+1].w};
            float A2[4] = {xv[r*4+2].x, xv[r*4+2].y, xv[r*4+2].z, xv[r*4+2].w};
            float A3[4] = {xv[r*4+3].x, xv[r*4+3].y, xv[r*4+3].z, xv[r*4+3].w};
            #pragma unroll
            for (int k = 0; k < 4; ++k) {
                u64 pk = (u64)f2bf(A0[k])
                       | ((u64)f2bf(A1[k]) << 16)
                       | ((u64)f2bf(A2[k]) << 32)
                       | ((u64)f2bf(A3[k]) << 48);
                *(u64*)(&Xt[w][swz_idx(e0 + k, t0)]) = pk;
            }
        }
    }

    __syncthreads();   // publish CBsh; stage buffers dead -> WS becomes Wl[8]

    // ================= band normalize (wave-private; lane i = row i) ============
    {
        float eci = ecsh[w][lane];
        float4 a03 = *(const float4*)(&Ab8[w][lane * 8]);
        float4 a47 = *(const float4*)(&Ab8[w][lane * 8 + 4]);
        float sc[7];
        #pragma unroll
        for (int s = 0; s < 7; ++s) {
            int src = lane - 1 - s;
            float p = (src >= 0) ? eci * ecsh[w][src] : 1.f;
            sc[s] = fminf(1.f, rsqrtf(p));   // 1/max(1,sqrt(p)); p=0 -> 1
        }
        a03.y *= sc[0]; a03.z *= sc[1]; a03.w *= sc[2];
        a47.x *= sc[3]; a47.y *= sc[4]; a47.z *= sc[5]; a47.w *= sc[6];
        *(float4*)(&Ab8[w][lane * 8]) = a03;
        *(float4*)(&Ab8[w][lane * 8 + 4]) = a47;
    }

    // ================= banded forward solve (lane j = column j) =================
    unsigned short* Wlw = WS + w * 4096;
    {
        const int j = lane;
        const float Dh = Dp[w];
        float mwin[7] = {0.f, 0.f, 0.f, 0.f, 0.f, 0.f, 0.f};
        float4 a03 = *(const float4*)(&Ab8[w][0]);      // {dn0, band row 0 (=0)}
        float4 a47 = *(const float4*)(&Ab8[w][4]);
        float cbv = bf2f(CBsh[j]);
        #pragma unroll 2
        for (int i = 0; i < 64; ++i) {
            float4 n03, n47;
            float ncb = 0.f;
            if (i < 63) {
                n03 = *(const float4*)(&Ab8[w][(i + 1) * 8]);
                n47 = *(const float4*)(&Ab8[w][(i + 1) * 8 + 4]);
                ncb = bf2f(CBsh[(i + 1) * 64 + j]);
            } else {
                n03 = make_float4(0.f, 0.f, 0.f, 0.f);
                n47 = n03;
            }
            float diag = (j == i) ? 1.f : 0.f;
            float t0 = fmaf(a03.y, mwin[0], fmaf(a03.z, mwin[1], diag));
            float t1 = fmaf(a03.w, mwin[2], fmaf(a47.x, mwin[3], a47.y * mwin[4]));
            float t2 = fmaf(a47.z, mwin[5], a47.w * mwin[6]);
            float mi_ = t0 + (t1 + t2);
            float wv = mi_ * cbv * a03.x;              // a03.x = dnorm[i]
            if (j == i) wv += Dh;
            Wlw[swz_idx(i, j)] = f2bf(wv);             // i uniform -> conflict-free
            #pragma unroll
            for (int s = 6; s > 0; --s) mwin[s] = mwin[s - 1];
            mwin[0] = mi_;
            a03 = n03; a47 = n47; cbv = ncb;
        }
    }

    // ================= y = W·X via MFMA (wave-private) ==========================
    {
        bf16x8 bfr[4][2];
        #pragma unroll
        for (int eb = 0; eb < 4; ++eb) {
            int er = eb * 16 + lm;
            bfr[eb][0] = *(const bf16x8*)(&Xt[w][swz_idx(er, quad * 8)]);
            bfr[eb][1] = *(const bf16x8*)(&Xt[w][swz_idx(er, 32 + quad * 8)]);
        }
        float* og = out + ((size_t)b * 64) * DIN + w * 64;
        #pragma unroll
        for (int m2 = 0; m2 < 4; ++m2) {
            int row0 = m2 * 16 + lm;
            bf16x8 a0 = *(const bf16x8*)(&Wlw[swz_idx(row0, quad * 8)]);
            bf16x8 a1 = *(const bf16x8*)(&Wlw[swz_idx(row0, 32 + quad * 8)]);
            f32x4 acc[4];
            #pragma unroll
            for (int eb = 0; eb < 4; ++eb) {
                f32x4 z = {0.f, 0.f, 0.f, 0.f};
                z = __builtin_amdgcn_mfma_f32_16x16x32_bf16(a0, bfr[eb][0], z, 0, 0, 0);
                z = __builtin_amdgcn_mfma_f32_16x16x32_bf16(a1, bfr[eb][1], z, 0, 0, 0);
                acc[eb] = z;
            }
            #pragma unroll
            for (int r = 0; r < 4; ++r) {
                int row = m2 * 16 + quad * 4 + r;
                #pragma unroll
                for (int eb = 0; eb < 4; ++eb)
                    og[(size_t)row * DIN + eb * 16 + lm] = acc[eb][r];
            }
        }
    }
}

extern "C" void kernel_launch(void* const* d_in, const int* in_sizes, int n_in,
                              void* d_out, int out_size, void* d_ws, size_t ws_size,
                              hipStream_t stream) {
    (void)in_sizes; (void)n_in; (void)out_size; (void)d_ws; (void)ws_size;
    dag_pipe_v6<<<dim3(NGRAPH), dim3(512), 0, stream>>>(
        (const float*)d_in[0],   // x
        (const float*)d_in[1],   // B
        (const float*)d_in[2],   // C
        (const float*)d_in[3],   // dt
        (const float*)d_in[4],   // dt_edge
        (const float*)d_in[5],   // dt_bias
        (const float*)d_in[6],   // D
        (const float*)d_in[7],   // dag_masks
        (const int*)d_in[8],     // edge_index
        (float*)d_out);
}

// Round 9
// 161.297 us; speedup vs baseline: 1.0925x; 1.0143x over previous
//
#include <hip/hip_runtime.h>
#include <math.h>

#define NGRAPH 256
#define HEADS  8
#define DIN    512
#define EPG    256   // edges per graph
#define NEDGE  65536
#define LOG2E 1.44269504088896341f
#define LN2   0.69314718055994531f

typedef short bf16x8 __attribute__((ext_vector_type(8)));
typedef float f32x4 __attribute__((ext_vector_type(4)));
typedef unsigned long long u64;

__device__ __forceinline__ float softplusf(float v) {
    if (v > 20.f) return v;
    float t = exp2f(v * LOG2E);
    return LN2 * log2f(1.f + t);
}
__device__ __forceinline__ unsigned short f2bf(float f) {   // RNE f32 -> bf16
    union { float f; unsigned u; } c; c.f = f;
    unsigned r = c.u + 0x7fffu + ((c.u >> 16) & 1u);
    return (unsigned short)(r >> 16);
}
__device__ __forceinline__ float bf2f(unsigned short h) {
    union { float f; unsigned u; } c; c.u = ((unsigned)h) << 16;
    return c.f;
}
__device__ __forceinline__ u64 pack4(float4 v) {            // 4 x RNE bf16 -> u64
    return (u64)f2bf(v.x) | ((u64)f2bf(v.y) << 16)
         | ((u64)f2bf(v.z) << 32) | ((u64)f2bf(v.w) << 48);
}
// XOR-swizzle for [64][64] bf16 tile (16B-group granularity) — Xt / Wl.
__device__ __forceinline__ int swz_idx(int row, int t) {
    int g = ((t >> 3) ^ (row ^ (row >> 3))) & 7;
    return (row << 6) | (g << 3) | (t & 7);
}
// XOR-swizzle for [64][128] bf16 tile: 16 groups/row; XOR low-3 bits of group
// index with row&7 (bijective per row; frag reads across 16 rows -> 2-way max).
__device__ __forceinline__ int swz128(int row, int col) {
    int g = col >> 3;
    int gs = (g & 8) | ((g ^ row) & 7);
    return row * 128 + (gs << 3) + (col & 7);
}

// One block per graph, 512 threads = 8 waves, wave w owns head w end-to-end.
// CB in single RNE bf16 (tolerance-justified: final GEMM is already bf16),
// 128-col ping-pong chunks (4 barriers), edge scatter interleaved into CB loop.
// LDS = 161,792 B.
__global__ __launch_bounds__(512, 2) void dag_v7(
        const float* __restrict__ x,
        const float* __restrict__ Bm,
        const float* __restrict__ Cm,
        const float* __restrict__ dt,
        const float* __restrict__ dt_edge,
        const float* __restrict__ dt_bias,
        const float* __restrict__ Dp,
        const float* __restrict__ dag_masks,
        const int* __restrict__ edge_index,
        float* __restrict__ out) {
    __shared__ __align__(16) unsigned short WS[32768];    // 64 KB: 2x(C,B) chunk tiles -> Wl[8][4096]
    __shared__ __align__(16) unsigned short Xt[HEADS][4096]; // X^T[e][t] bf16 swizzled, 64 KB
    __shared__ __align__(16) unsigned short CBsh[4096];   // CB[i][t] bf16 linear, 8 KB
    __shared__ __align__(16) float Ab8[HEADS][512];       // [i][8]: slot0=dnorm, 1-7=band, 16 KB
    __shared__ float dts[HEADS][64];
    __shared__ float dtt[HEADS][64];
    __shared__ float ecsh[HEADS][64];                     // per-head replica (wave-private)

    const int b = blockIdx.x;
    const int tid = threadIdx.x;
    const int w = tid >> 6;       // wave id == head id
    const int lane = tid & 63;
    const int lm = lane & 15;
    const int quad = lane >> 4;
    const float bias = dt_bias[w];

    // ================= entry loads =================
    float2 dv = *(const float2*)(dt + ((size_t)(b * 64 + lane)) * 16 + w * 2);

    int esl[4], edl[4]; float emk[4], edr[4];
    #pragma unroll
    for (int eo = 0; eo < 4; ++eo) {
        int e = b * EPG + eo * 64 + lane;
        esl[eo] = edge_index[e];
        edl[eo] = edge_index[NEDGE + e];
        emk[eo] = dag_masks[e];
        edr[eo] = dt_edge[(size_t)e * HEADS + w];
    }

    // CB stage addressing: thread covers 16 consecutive floats of row srow
    // (cols scol..scol+15 within the 128-col chunk) for BOTH C and B.
    const int srow = tid >> 3;
    const int scol = (tid & 7) << 4;
    const float* Cp = Cm + ((size_t)(b * 64 + srow)) * DIN + scol;
    const float* Bp = Bm + ((size_t)(b * 64 + srow)) * DIN + scol;
    float4 pre[8];                       // chunk in flight: [0..3]=C, [4..7]=B
    #pragma unroll
    for (int i = 0; i < 4; ++i) {
        pre[i]     = *(const float4*)(Cp + 4 * i);
        pre[4 + i] = *(const float4*)(Bp + 4 * i);
    }

    // ================= phase 0 (wave-private) =================
    dts[w][lane] = softplusf(dv.x + bias);
    dtt[w][lane] = softplusf(dv.y + bias);
    ecsh[w][lane] = 0.f;
    {
        float4 z = make_float4(0.f, 0.f, 0.f, 0.f);
        *(float4*)(&Ab8[w][lane * 8]) = z;
        *(float4*)(&Ab8[w][lane * 8 + 4]) = z;
    }

    // ================= CB = C·B^T (single RNE bf16), 4 x 128-col chunks =========
    // wave w computes rows [16*mi,16*mi+16) x cols [16*ni0, 16*ni0+32)
    const int mi = w >> 1;
    const int ni0 = (w & 1) * 2;
    f32x4 acc0 = {0.f, 0.f, 0.f, 0.f};
    f32x4 acc1 = {0.f, 0.f, 0.f, 0.f};
    float4 xv[16];                       // x tile loads issued in chunk-3 slot
    #pragma unroll
    for (int c = 0; c < 4; ++c) {
        unsigned short* buf = WS + (c & 1) * 16384;
        // write chunk c from registers (RNE bf16)
        #pragma unroll
        for (int i = 0; i < 4; ++i) {
            int col = scol + 4 * i;
            *(u64*)(buf + swz128(srow, col))        = pack4(pre[i]);
            *(u64*)(buf + 8192 + swz128(srow, col)) = pack4(pre[4 + i]);
        }
        if (c < 3) {     // prefetch chunk c+1
            #pragma unroll
            for (int i = 0; i < 4; ++i) {
                pre[i]     = *(const float4*)(Cp + (c + 1) * 128 + 4 * i);
                pre[4 + i] = *(const float4*)(Bp + (c + 1) * 128 + 4 * i);
            }
        } else {         // last chunk: issue x-tile loads instead
            const float* xg = x + (size_t)b * 64 * DIN + w * 64;
            #pragma unroll
            for (int r = 0; r < 4; ++r) {
                int t0 = quad * 4 + r * 16;
                #pragma unroll
                for (int k = 0; k < 4; ++k)
                    xv[r * 4 + k] = *(const float4*)(xg + (size_t)(t0 + k) * DIN + lm * 4);
            }
        }
        __syncthreads();    // publish chunk c
        #pragma unroll
        for (int ks = 0; ks < 4; ++ks) {
            int kl = ks * 32 + quad * 8;
            bf16x8 ah = *(const bf16x8*)(buf + swz128(mi * 16 + lm, kl));
            bf16x8 b0 = *(const bf16x8*)(buf + 8192 + swz128(ni0 * 16 + lm, kl));
            bf16x8 b1 = *(const bf16x8*)(buf + 8192 + swz128((ni0 + 1) * 16 + lm, kl));
            acc0 = __builtin_amdgcn_mfma_f32_16x16x32_bf16(ah, b0, acc0, 0, 0, 0);
            acc1 = __builtin_amdgcn_mfma_f32_16x16x32_bf16(ah, b1, acc1, 0, 0, 0);
        }
        // edge c scatter (wave-private; overlaps next chunk's staging)
        {
            int sl = esl[c] & 63;
            int dl = edl[c] & 63;
            float de = softplusf(edr[c] + bias);
            float dsum = (dts[w][sl] + dtt[w][dl] + de) * 0.57735026918962576451f; // 1/sqrt(3)
            float dexp = exp2f(-dsum * LOG2E);
            atomicAdd(&Ab8[w][dl * 8 + (dl - sl)], dexp * emk[c]);   // dl-sl in [1,7]
            atomicAdd(&Ab8[w][dl * 8], dsum * emk[c]);               // dnorm in slot 0
            atomicAdd(&ecsh[w][dl], emk[c]);
        }
    }
    // C/D layout: col = lane&15, row = quad*4 + r
    #pragma unroll
    for (int r = 0; r < 4; ++r) {
        int row = mi * 16 + quad * 4 + r;
        CBsh[row * 64 + ni0 * 16 + lm] = f2bf(acc0[r]);
        CBsh[row * 64 + (ni0 + 1) * 16 + lm] = f2bf(acc1[r]);
    }

    // ================= Xt convert+write from regs (wave-private) ================
    {
        int e0 = lm * 4;
        #pragma unroll
        for (int r = 0; r < 4; ++r) {
            int t0 = quad * 4 + r * 16;
            float A0[4] = {xv[r*4+0].x, xv[r*4+0].y, xv[r*4+0].z, xv[r*4+0].w};
            float A1[4] = {xv[r*4+1].x, xv[r*4+1].y, xv[r*4+1].z, xv[r*4+1].w};
            float A2[4] = {xv[r*4+2].x, xv[r*4+2].y, xv[r*4+2].z, xv[r*4+2].w};
            float A3[4] = {xv[r*4+3].x, xv[r*4+3].y, xv[r*4+3].z, xv[r*4+3].w};
            #pragma unroll
            for (int k = 0; k < 4; ++k) {
                u64 pk = (u64)f2bf(A0[k])
                       | ((u64)f2bf(A1[k]) << 16)
                       | ((u64)f2bf(A2[k]) << 32)
                       | ((u64)f2bf(A3[k]) << 48);
                *(u64*)(&Xt[w][swz_idx(e0 + k, t0)]) = pk;
            }
        }
    }

    __syncthreads();   // publish CBsh; stage buffers dead -> WS becomes Wl[8]

    // ================= band normalize (wave-private; lane i = row i) ============
    {
        float eci = ecsh[w][lane];
        float4 a03 = *(const float4*)(&Ab8[w][lane * 8]);
        float4 a47 = *(const float4*)(&Ab8[w][lane * 8 + 4]);
        float sc[7];
        #pragma unroll
        for (int s = 0; s < 7; ++s) {
            int src = lane - 1 - s;
            float p = (src >= 0) ? eci * ecsh[w][src] : 1.f;
            sc[s] = fminf(1.f, rsqrtf(p));   // 1/max(1,sqrt(p)); p=0 -> 1
        }
        a03.y *= sc[0]; a03.z *= sc[1]; a03.w *= sc[2];
        a47.x *= sc[3]; a47.y *= sc[4]; a47.z *= sc[5]; a47.w *= sc[6];
        *(float4*)(&Ab8[w][lane * 8]) = a03;
        *(float4*)(&Ab8[w][lane * 8 + 4]) = a47;
    }

    // ================= GEMM B-frags preloaded BEFORE the solve ==================
    bf16x8 bfr[4][2];
    #pragma unroll
    for (int eb = 0; eb < 4; ++eb) {
        int er = eb * 16 + lm;
        bfr[eb][0] = *(const bf16x8*)(&Xt[w][swz_idx(er, quad * 8)]);
        bfr[eb][1] = *(const bf16x8*)(&Xt[w][swz_idx(er, 32 + quad * 8)]);
    }

    // ================= banded forward solve (lane j = column j) =================
    unsigned short* Wlw = WS + w * 4096;
    {
        const int j = lane;
        const float Dh = Dp[w];
        float mwin[7] = {0.f, 0.f, 0.f, 0.f, 0.f, 0.f, 0.f};
        float4 a03 = *(const float4*)(&Ab8[w][0]);      // {dn0, band row 0 (=0)}
        float4 a47 = *(const float4*)(&Ab8[w][4]);
        float cbv = bf2f(CBsh[j]);
        #pragma unroll 2
        for (int i = 0; i < 64; ++i) {
            float4 n03, n47;
            float ncb = 0.f;
            if (i < 63) {
                n03 = *(const float4*)(&Ab8[w][(i + 1) * 8]);
                n47 = *(const float4*)(&Ab8[w][(i + 1) * 8 + 4]);
                ncb = bf2f(CBsh[(i + 1) * 64 + j]);
            } else {
                n03 = make_float4(0.f, 0.f, 0.f, 0.f);
                n47 = n03;
            }
            float diag = (j == i) ? 1.f : 0.f;
            float t0 = fmaf(a03.y, mwin[0], fmaf(a03.z, mwin[1], diag));
            float t1 = fmaf(a03.w, mwin[2], fmaf(a47.x, mwin[3], a47.y * mwin[4]));
            float t2 = fmaf(a47.z, mwin[5], a47.w * mwin[6]);
            float mi_ = t0 + (t1 + t2);
            float wv = mi_ * cbv * a03.x;              // a03.x = dnorm[i]
            if (j == i) wv += Dh;
            Wlw[swz_idx(i, j)] = f2bf(wv);             // i uniform -> conflict-free
            #pragma unroll
            for (int s = 6; s > 0; --s) mwin[s] = mwin[s - 1];
            mwin[0] = mi_;
            a03 = n03; a47 = n47; cbv = ncb;
        }
    }

    // ================= y = W·X via MFMA (wave-private) ==========================
    {
        float* og = out + ((size_t)b * 64) * DIN + w * 64;
        #pragma unroll
        for (int m2 = 0; m2 < 4; ++m2) {
            int row0 = m2 * 16 + lm;
            bf16x8 a0 = *(const bf16x8*)(&Wlw[swz_idx(row0, quad * 8)]);
            bf16x8 a1 = *(const bf16x8*)(&Wlw[swz_idx(row0, 32 + quad * 8)]);
            f32x4 acc[4];
            #pragma unroll
            for (int eb = 0; eb < 4; ++eb) {
                f32x4 z = {0.f, 0.f, 0.f, 0.f};
                z = __builtin_amdgcn_mfma_f32_16x16x32_bf16(a0, bfr[eb][0], z, 0, 0, 0);
                z = __builtin_amdgcn_mfma_f32_16x16x32_bf16(a1, bfr[eb][1], z, 0, 0, 0);
                acc[eb] = z;
            }
            #pragma unroll
            for (int r = 0; r < 4; ++r) {
                int row = m2 * 16 + quad * 4 + r;
                #pragma unroll
                for (int eb = 0; eb < 4; ++eb)
                    og[(size_t)row * DIN + eb * 16 + lm] = acc[eb][r];
            }
        }
    }
}

extern "C" void kernel_launch(void* const* d_in, const int* in_sizes, int n_in,
                              void* d_out, int out_size, void* d_ws, size_t ws_size,
                              hipStream_t stream) {
    (void)in_sizes; (void)n_in; (void)out_size; (void)d_ws; (void)ws_size;
    dag_v7<<<dim3(NGRAPH), dim3(512), 0, stream>>>(
        (const float*)d_in[0],   // x
        (const float*)d_in[1],   // B
        (const float*)d_in[2],   // C
        (const float*)d_in[3],   // dt
        (const float*)d_in[4],   // dt_edge
        (const float*)d_in[5],   // dt_bias
        (const float*)d_in[6],   // D
        (const float*)d_in[7],   // dag_masks
        (const int*)d_in[8],     // edge_index
        (float*)d_out);
}